// Round 2
// baseline (287.597 us; speedup 1.0000x reference)
//
#include <hip/hip_runtime.h>
#include <cstdint>

#define KK 16384   // C*T
#define EE 256     // output features
#define LRELU_ALPHA 0.2f

typedef __bf16 bf16x8 __attribute__((ext_vector_type(8)));
typedef float f32x4 __attribute__((ext_vector_type(4)));

// ws layout (bytes):
//   [0, 2 MB)        : Wh f32 [256 o][2048 m]  (m = mt*64 + local, 56 rows/8n used)
//   [2 MB, 10 MB)    : Wt bf16 [256][16384]
#define WH_OFF 0u
#define WT_OFF (256u*2048u*4u)

__device__ __forceinline__ unsigned short f2bf(float f){
  union { float f; unsigned u; } x; x.f = f;
  unsigned r = x.u + 0x7fffu + ((x.u >> 16) & 1u);
  return (unsigned short)(r >> 16);
}

// ---------------- Kernel 1: W (16384x256 f32) -> Wt (256x16384 bf16), + zero Wh ----------------
__global__ __launch_bounds__(256) void k_transpose_w(const float* __restrict__ W,
                                                     unsigned short* __restrict__ Wt,
                                                     float* __restrict__ Wh){
  __shared__ float tile[64][65];
  const int i0 = blockIdx.x * 64;
  const int o0 = blockIdx.y * 64;
  const int tid = threadIdx.x;

  // zero the Wh accumulator (1024 blocks x 256 threads x 8 B = 2 MB)
  const int bid = blockIdx.y * gridDim.x + blockIdx.x;
  reinterpret_cast<float2*>(Wh)[bid * 256 + tid] = make_float2(0.f, 0.f);

  #pragma unroll
  for (int r = 0; r < 16; ++r){
    int il = r*4 + (tid >> 6);
    int ol = tid & 63;
    tile[il][ol] = W[(size_t)(i0+il)*EE + o0 + ol];
  }
  __syncthreads();
  #pragma unroll
  for (int r = 0; r < 16; ++r){
    int ol = r*4 + (tid >> 6);
    int il = tid & 63;
    Wt[(size_t)(o0+ol)*KK + i0 + il] = f2bf(tile[il][ol]);
  }
}

// ---------------- Kernel 2: main GEMM, split-K=32, atomic f32 epilogue ----------------
// D[o][m] = sum_k Wt[o][k] * hf[m][k],  m = (n0+nn)*7+v rows (56 used, 64 padded)
// grid: (32 mtiles, 32 kchunks), 256 threads; each block does K=512 (8 c-planes)
__global__ __launch_bounds__(256) void k_gemm(const float* __restrict__ h,
                                              const unsigned short* __restrict__ Wt,
                                              float* __restrict__ Wh){
  __shared__ unsigned short As[256*72]; // Wt tile: o x k, stride 72
  __shared__ unsigned short Bs[64*72];  // h tile:  m x k, stride 72
  const int tid  = threadIdx.x;
  const int mt   = blockIdx.x;  // 0..31
  const int kc   = blockIdx.y;  // 0..31
  const int n0   = mt * 8;
  const int w    = tid >> 6;
  const int lane = tid & 63;
  const int col  = lane & 15;
  const int quad = lane >> 4;

  // zero pad rows (m = 56..63) once; staging never touches them
  for (int idx = tid; idx < 8*72; idx += 256) Bs[56*72 + idx] = 0;

  // h staging: 8 rows x 448 contiguous floats = 896 float4 per c-plane
  // hoisted offsets (s-invariant except + c*448)
  int hoff[4]; int hlds[4][4]; bool hval[4];
  #pragma unroll
  for (int it = 0; it < 4; ++it){
    int j = tid + it*256;
    hval[it] = (j < 896);
    int jj = hval[it] ? j : 0;
    int nn = jj / 112;
    int f  = jj - nn*112;
    hoff[it] = (n0+nn)*114688 + f*4;   // + c*448 later
    #pragma unroll
    for (int e = 0; e < 4; ++e){
      int rr = f*4 + e;
      int t_ = rr / 7;
      int v_ = rr - t_*7;
      hlds[it][e] = (nn*7 + v_)*72 + t_;
    }
  }
  const int wo = tid >> 3;        // 0..31
  const int wk = (tid & 7) * 8;   // 0..56

  f32x4 acc[4][4];
  #pragma unroll
  for (int a_ = 0; a_ < 4; ++a_)
    #pragma unroll
    for (int b_ = 0; b_ < 4; ++b_)
      acc[a_][b_] = (f32x4){0.f, 0.f, 0.f, 0.f};

  for (int s = 0; s < 8; ++s){
    const int c  = kc*8 + s;
    const int i0 = c*64;
    // stage Wt tile: 256 o x 64 k (bf16, float4 = 8 shorts)
    {
      const unsigned short* src = Wt + (size_t)wo*KK + i0 + wk;
      #pragma unroll
      for (int r = 0; r < 8; ++r){
        float4 v = *reinterpret_cast<const float4*>(src + (size_t)r*32*KK);
        *reinterpret_cast<float4*>(&As[(wo + r*32)*72 + wk]) = v;
      }
    }
    // stage h tile: float4 loads of contiguous (n,c) rows -> transposed bf16
    {
      const int cb = c*448;
      #pragma unroll
      for (int it = 0; it < 4; ++it){
        if (hval[it]){
          float4 v = *reinterpret_cast<const float4*>(h + (size_t)(hoff[it] + cb));
          Bs[hlds[it][0]] = f2bf(v.x);
          Bs[hlds[it][1]] = f2bf(v.y);
          Bs[hlds[it][2]] = f2bf(v.z);
          Bs[hlds[it][3]] = f2bf(v.w);
        }
      }
    }
    __syncthreads();
    #pragma unroll
    for (int kh = 0; kh < 2; ++kh){
      bf16x8 af[4], bfr[4];
      #pragma unroll
      for (int oi = 0; oi < 4; ++oi)
        af[oi] = *reinterpret_cast<const bf16x8*>(&As[(w*64 + oi*16 + col)*72 + kh*32 + quad*8]);
      #pragma unroll
      for (int mi = 0; mi < 4; ++mi)
        bfr[mi] = *reinterpret_cast<const bf16x8*>(&Bs[(mi*16 + col)*72 + kh*32 + quad*8]);
      #pragma unroll
      for (int oi = 0; oi < 4; ++oi)
        #pragma unroll
        for (int mi = 0; mi < 4; ++mi)
          acc[oi][mi] = __builtin_amdgcn_mfma_f32_16x16x32_bf16(af[oi], bfr[mi], acc[oi][mi], 0, 0, 0);
    }
    __syncthreads();
  }

  // atomic accumulate into Wh[o][m]; lanes 0-15 of each (oi,mi,r) hit 16
  // consecutive dwords (one 64B line)
  #pragma unroll
  for (int oi = 0; oi < 4; ++oi){
    #pragma unroll
    for (int r = 0; r < 4; ++r){
      int o = w*64 + oi*16 + quad*4 + r;
      size_t rowbase = (size_t)o*2048 + mt*64;
      #pragma unroll
      for (int mi = 0; mi < 4; ++mi)
        atomicAdd(&Wh[rowbase + mi*16 + col], acc[oi][mi][r]);
    }
  }
}

// ---------------- Kernel 3: attention + elu (adj-norm folded in) ----------------
// one block per n, thread = output feature o
__global__ __launch_bounds__(256) void k_attn(const float* __restrict__ Wh,
                                              const float* __restrict__ a,
                                              const float* __restrict__ Bp,
                                              float* __restrict__ out){
  const int n    = blockIdx.x;
  const int tid  = threadIdx.x;
  const int lane = tid & 63;
  const int wv   = tid >> 6;
  const int bm   = (n >> 3)*64 + (n & 7)*7;

  __shared__ float adjn[49];
  __shared__ float red1[4][7], red2[4][7];
  __shared__ float s1s[7], s2s[7];
  __shared__ float att0[49], att[49];

  if (tid == 0){
    float adj[49];
    float mn = 1e30f, mx = -1e30f;
    for (int i = 0; i < 7; ++i)
      for (int j = 0; j < 7; ++j){
        float x = Bp[i*7+j] + 1e-6f + (i == j ? 1.f : 0.f);
        adj[i*7+j] = x;
        mn = fminf(mn, x); mx = fmaxf(mx, x);
      }
    float inv = 1.f / (mx - mn);
    for (int i = 0; i < 49; ++i) adj[i] = (adj[i] - mn) * inv;
    float d12[7];
    for (int i = 0; i < 7; ++i){
      float s = 0.f;
      for (int j = 0; j < 7; ++j) s += adj[i*7+j];
      d12[i] = 1.f / sqrtf(s);
    }
    for (int i = 0; i < 7; ++i)
      for (int j = 0; j < 7; ++j)
        adjn[i*7+j] = d12[i] * adj[i*7+j] * d12[j];
  }

  float wh[7];
  #pragma unroll
  for (int v = 0; v < 7; ++v)
    wh[v] = Wh[(size_t)tid*2048 + bm + v];

  const float a1 = a[tid];
  const float a2 = a[256 + tid];

  #pragma unroll
  for (int v = 0; v < 7; ++v){
    float x1 = wh[v]*a1;
    float x2 = wh[v]*a2;
    #pragma unroll
    for (int off = 32; off > 0; off >>= 1){
      x1 += __shfl_down(x1, off);
      x2 += __shfl_down(x2, off);
    }
    if (lane == 0){ red1[wv][v] = x1; red2[wv][v] = x2; }
  }
  __syncthreads();
  if (tid < 7){
    s1s[tid] = red1[0][tid]+red1[1][tid]+red1[2][tid]+red1[3][tid];
    s2s[tid] = red2[0][tid]+red2[1][tid]+red2[2][tid]+red2[3][tid];
  }
  __syncthreads();
  if (tid < 7){
    const int v = tid;
    float e[7]; float mx = -1e30f;
    #pragma unroll
    for (int u = 0; u < 7; ++u){
      float t = s1s[v] + s2s[u];
      t = t > 0.f ? t : LRELU_ALPHA*t;
      e[u] = t; mx = fmaxf(mx, t);
    }
    float sum = 0.f;
    #pragma unroll
    for (int u = 0; u < 7; ++u){ e[u] = expf(e[u]-mx); sum += e[u]; }
    float inv = 1.f/sum;
    #pragma unroll
    for (int u = 0; u < 7; ++u) att0[v*7+u] = e[u]*inv;
  }
  __syncthreads();
  if (tid < 7){
    const int v = tid;
    #pragma unroll
    for (int u = 0; u < 7; ++u){
      float s = 0.f;
      #pragma unroll
      for (int w7 = 0; w7 < 7; ++w7) s += adjn[v*7+w7]*att0[w7*7+u];
      att[v*7+u] = s;
    }
  }
  __syncthreads();
  #pragma unroll
  for (int v = 0; v < 7; ++v){
    float hp = 0.f;
    #pragma unroll
    for (int u = 0; u < 7; ++u) hp += att[v*7+u]*wh[u];
    float o = hp > 0.f ? hp : expm1f(hp);
    out[(size_t)(n*7+v)*256 + tid] = o;
  }
}

extern "C" void kernel_launch(void* const* d_in, const int* in_sizes, int n_in,
                              void* d_out, int out_size, void* d_ws, size_t ws_size,
                              hipStream_t stream){
  const float* h  = (const float*)d_in[0];
  const float* W  = (const float*)d_in[1];
  const float* a  = (const float*)d_in[2];
  const float* Bp = (const float*)d_in[3];
  float* out = (float*)d_out;
  char* ws = (char*)d_ws;
  float*          Wh = (float*)(ws + WH_OFF);
  unsigned short* Wt = (unsigned short*)(ws + WT_OFF);

  k_transpose_w<<<dim3(256, 4), 256, 0, stream>>>(W, Wt, Wh);
  k_gemm<<<dim3(32, 32), 256, 0, stream>>>(h, Wt, Wh);
  k_attn<<<256, 256, 0, stream>>>(Wh, a, Bp, out);
}

// Round 3
// 223.247 us; speedup vs baseline: 1.2882x; 1.2882x over previous
//
#include <hip/hip_runtime.h>
#include <cstdint>

#define KK 16384   // C*T
#define EE 256     // output features
#define M_USED 1792
#define LRELU_ALPHA 0.2f

typedef __bf16 bf16x8 __attribute__((ext_vector_type(8)));
typedef float f32x4 __attribute__((ext_vector_type(4)));

// ws layout (bytes):
//   [0, 8 MB)                 : Wt bf16 [256][16384]      (o-major, k-contiguous)
//   [WT, WT + nkc*1.84 MB)    : partial f32 [nkc][256][1792]
//   [after part, +1.84 MB)    : Wh f32 [256][1792]
#define WT_BYTES (256u*16384u*2u)

__device__ __forceinline__ unsigned short f2bf(float f){
  union { float f; unsigned u; } x; x.f = f;
  unsigned r = x.u + 0x7fffu + ((x.u >> 16) & 1u);
  return (unsigned short)(r >> 16);
}

// ---------------- Kernel 1: W (16384x256 f32) -> Wt (256x16384 bf16) ----------------
__global__ __launch_bounds__(256) void k_transpose_w(const float* __restrict__ W,
                                                     unsigned short* __restrict__ Wt){
  __shared__ float tile[64][65];
  const int i0 = blockIdx.x * 64;
  const int o0 = blockIdx.y * 64;
  const int tid = threadIdx.x;
  #pragma unroll
  for (int r = 0; r < 16; ++r){
    int il = r*4 + (tid >> 6);
    int ol = tid & 63;
    tile[il][ol] = W[(size_t)(i0+il)*EE + o0 + ol];
  }
  __syncthreads();
  #pragma unroll
  for (int r = 0; r < 16; ++r){
    int ol = r*4 + (tid >> 6);
    int il = tid & 63;
    Wt[(size_t)(o0+ol)*KK + i0 + il] = f2bf(tile[il][ol]);
  }
}

// ---------------- Kernel 2: GEMM. A-frags direct from global (L2), only h through LDS ----------
// D[o][m] = sum_k Wt[o][k] * hf[m][k],  m-tile = 8 n's x 7 v (56 used, 64 padded)
// grid (32 mt, nkc kchunks), 512 threads (8 waves); wave w owns o-rows [w*32, w*32+32)
__global__ __launch_bounds__(512) void k_gemm(const float* __restrict__ h,
                                              const unsigned short* __restrict__ Wt,
                                              float* __restrict__ part, int planes){
  __shared__ unsigned short Bs[64*72];  // h tile: m x k, stride 72
  const int tid  = threadIdx.x;
  const int mt   = blockIdx.x;
  const int kc   = blockIdx.y;
  const int n0   = mt * 8;
  const int w    = tid >> 6;
  const int lane = tid & 63;
  const int col  = lane & 15;
  const int quad = lane >> 4;

  // zero pad rows (m = 56..63) once; staging never touches them
  for (int idx = tid; idx < 8*72; idx += 512) Bs[56*72 + idx] = 0;

  // h staging: 8 n-rows x 448 contiguous floats = 896 float4 per c-plane, 512 threads
  int hoff[2]; int hlds[2][4]; bool hval[2];
  #pragma unroll
  for (int it = 0; it < 2; ++it){
    int j = tid + it*512;
    hval[it] = (j < 896);
    int jj = hval[it] ? j : 0;
    int nn = jj / 112;          // 112 float4 per (n, c) row
    int f  = jj - nn*112;
    hoff[it] = (n0+nn)*114688 + f*4;   // + c*448 later
    #pragma unroll
    for (int e = 0; e < 4; ++e){
      int rr = f*4 + e;
      int t_ = rr / 7;
      int v_ = rr - t_*7;
      hlds[it][e] = (nn*7 + v_)*72 + t_;
    }
  }

  // A-frag global base: rows (w*32 + oi*16 + col), 64 contiguous bytes per (c, kh)
  const unsigned short* aptr = Wt + (size_t)(w*32 + col)*KK + quad*8;

  f32x4 acc[2][4];
  #pragma unroll
  for (int a_ = 0; a_ < 2; ++a_)
    #pragma unroll
    for (int b_ = 0; b_ < 4; ++b_)
      acc[a_][b_] = (f32x4){0.f, 0.f, 0.f, 0.f};

  const int c0 = kc * planes;
  for (int s = 0; s < planes; ++s){
    const int c = c0 + s;
    // stage h tile: float4 loads of contiguous (n,c) rows -> transposed bf16
    {
      const int cb = c*448;
      #pragma unroll
      for (int it = 0; it < 2; ++it){
        if (hval[it]){
          float4 v = *reinterpret_cast<const float4*>(h + (size_t)(hoff[it] + cb));
          Bs[hlds[it][0]] = f2bf(v.x);
          Bs[hlds[it][1]] = f2bf(v.y);
          Bs[hlds[it][2]] = f2bf(v.z);
          Bs[hlds[it][3]] = f2bf(v.w);
        }
      }
    }
    // A-frags from global (no barrier dependency)
    bf16x8 af[2][2];
    #pragma unroll
    for (int oi = 0; oi < 2; ++oi)
      #pragma unroll
      for (int kh = 0; kh < 2; ++kh)
        af[oi][kh] = *reinterpret_cast<const bf16x8*>(aptr + (size_t)oi*16*KK + c*64 + kh*32);
    __syncthreads();
    #pragma unroll
    for (int kh = 0; kh < 2; ++kh){
      bf16x8 bfr[4];
      #pragma unroll
      for (int mi = 0; mi < 4; ++mi)
        bfr[mi] = *reinterpret_cast<const bf16x8*>(&Bs[(mi*16 + col)*72 + kh*32 + quad*8]);
      #pragma unroll
      for (int oi = 0; oi < 2; ++oi)
        #pragma unroll
        for (int mi = 0; mi < 4; ++mi)
          acc[oi][mi] = __builtin_amdgcn_mfma_f32_16x16x32_bf16(af[oi][kh], bfr[mi], acc[oi][mi], 0, 0, 0);
    }
    __syncthreads();
  }

  // partials: part[kc][o][mt*56 + m_local], m_local < 56 (coalesced, masked tail)
  #pragma unroll
  for (int oi = 0; oi < 2; ++oi){
    #pragma unroll
    for (int r = 0; r < 4; ++r){
      int o = w*32 + oi*16 + quad*4 + r;
      size_t rowbase = ((size_t)(kc*256 + o))*M_USED + mt*56;
      #pragma unroll
      for (int mi = 0; mi < 4; ++mi){
        int ml = mi*16 + col;
        if (ml < 56) part[rowbase + ml] = acc[oi][mi][r];
      }
    }
  }
}

// ---------------- Kernel 3: reduce partials over kc (coalesced in m) ----------------
// grid (7, 256): m = bx*256+tid, o = by
__global__ __launch_bounds__(256) void k_reduce(const float* __restrict__ part,
                                                float* __restrict__ Wh, int nkc){
  const int m = blockIdx.x*256 + threadIdx.x;
  const int o = blockIdx.y;
  float s = 0.f;
  for (int k = 0; k < nkc; ++k)
    s += part[((size_t)(k*256 + o))*M_USED + m];
  Wh[(size_t)o*M_USED + m] = s;
}

// ---------------- Kernel 4: attention + elu (adj-norm folded in) ----------------
__global__ __launch_bounds__(256) void k_attn(const float* __restrict__ Wh,
                                              const float* __restrict__ a,
                                              const float* __restrict__ Bp,
                                              float* __restrict__ out){
  const int n    = blockIdx.x;
  const int tid  = threadIdx.x;
  const int lane = tid & 63;
  const int wv   = tid >> 6;

  __shared__ float adjn[49];
  __shared__ float red1[4][7], red2[4][7];
  __shared__ float s1s[7], s2s[7];
  __shared__ float att0[49], att[49];

  if (tid == 0){
    float adj[49];
    float mn = 1e30f, mx = -1e30f;
    for (int i = 0; i < 7; ++i)
      for (int j = 0; j < 7; ++j){
        float x = Bp[i*7+j] + 1e-6f + (i == j ? 1.f : 0.f);
        adj[i*7+j] = x;
        mn = fminf(mn, x); mx = fmaxf(mx, x);
      }
    float inv = 1.f / (mx - mn);
    for (int i = 0; i < 49; ++i) adj[i] = (adj[i] - mn) * inv;
    float d12[7];
    for (int i = 0; i < 7; ++i){
      float s = 0.f;
      for (int j = 0; j < 7; ++j) s += adj[i*7+j];
      d12[i] = 1.f / sqrtf(s);
    }
    for (int i = 0; i < 7; ++i)
      for (int j = 0; j < 7; ++j)
        adjn[i*7+j] = d12[i] * adj[i*7+j] * d12[j];
  }

  float wh[7];
  #pragma unroll
  for (int v = 0; v < 7; ++v)
    wh[v] = Wh[(size_t)tid*M_USED + n*7 + v];

  const float a1 = a[tid];
  const float a2 = a[256 + tid];

  #pragma unroll
  for (int v = 0; v < 7; ++v){
    float x1 = wh[v]*a1;
    float x2 = wh[v]*a2;
    #pragma unroll
    for (int off = 32; off > 0; off >>= 1){
      x1 += __shfl_down(x1, off);
      x2 += __shfl_down(x2, off);
    }
    if (lane == 0){ red1[wv][v] = x1; red2[wv][v] = x2; }
  }
  __syncthreads();
  if (tid < 7){
    s1s[tid] = red1[0][tid]+red1[1][tid]+red1[2][tid]+red1[3][tid];
    s2s[tid] = red2[0][tid]+red2[1][tid]+red2[2][tid]+red2[3][tid];
  }
  __syncthreads();
  if (tid < 7){
    const int v = tid;
    float e[7]; float mx = -1e30f;
    #pragma unroll
    for (int u = 0; u < 7; ++u){
      float t = s1s[v] + s2s[u];
      t = t > 0.f ? t : LRELU_ALPHA*t;
      e[u] = t; mx = fmaxf(mx, t);
    }
    float sum = 0.f;
    #pragma unroll
    for (int u = 0; u < 7; ++u){ e[u] = expf(e[u]-mx); sum += e[u]; }
    float inv = 1.f/sum;
    #pragma unroll
    for (int u = 0; u < 7; ++u) att0[v*7+u] = e[u]*inv;
  }
  __syncthreads();
  if (tid < 7){
    const int v = tid;
    #pragma unroll
    for (int u = 0; u < 7; ++u){
      float s = 0.f;
      #pragma unroll
      for (int w7 = 0; w7 < 7; ++w7) s += adjn[v*7+w7]*att0[w7*7+u];
      att[v*7+u] = s;
    }
  }
  __syncthreads();
  #pragma unroll
  for (int v = 0; v < 7; ++v){
    float hp = 0.f;
    #pragma unroll
    for (int u = 0; u < 7; ++u) hp += att[v*7+u]*wh[u];
    float o = hp > 0.f ? hp : expm1f(hp);
    out[(size_t)(n*7+v)*256 + tid] = o;
  }
}

extern "C" void kernel_launch(void* const* d_in, const int* in_sizes, int n_in,
                              void* d_out, int out_size, void* d_ws, size_t ws_size,
                              hipStream_t stream){
  const float* h  = (const float*)d_in[0];
  const float* W  = (const float*)d_in[1];
  const float* a  = (const float*)d_in[2];
  const float* Bp = (const float*)d_in[3];
  float* out = (float*)d_out;
  char* ws = (char*)d_ws;

  const size_t part_elems = (size_t)256 * M_USED;              // per kchunk
  const size_t need16 = WT_BYTES + (16 + 1) * part_elems * 4;  // ~39.6 MB
  const int nkc = (ws_size >= need16) ? 16 : 8;                // fallback 8 needs ~24.9 MB

  unsigned short* Wt   = (unsigned short*)ws;
  float*          part = (float*)(ws + WT_BYTES);
  float*          Wh   = part + (size_t)nkc * part_elems;

  k_transpose_w<<<dim3(256, 4), 256, 0, stream>>>(W, Wt);
  k_gemm<<<dim3(32, nkc), 512, 0, stream>>>(h, Wt, part, 256/nkc);
  k_reduce<<<dim3(7, 256), 256, 0, stream>>>(part, Wh, nkc);
  k_attn<<<256, 256, 0, stream>>>(Wh, a, Bp, out);
}

// Round 4
// 216.594 us; speedup vs baseline: 1.3278x; 1.0307x over previous
//
#include <hip/hip_runtime.h>
#include <cstdint>

#define KK 16384   // C*T
#define EE 256     // output features
#define M_USED 1792
#define LRELU_ALPHA 0.2f

typedef __bf16 bf16x8 __attribute__((ext_vector_type(8)));
typedef float f32x4 __attribute__((ext_vector_type(4)));

// ws layout (bytes):
//   [0, 8 MB)                 : Wt bf16 [256][16384]      (o-major, k-contiguous)
//   [WT, WT + nkc*1.84 MB)    : partial f32 [nkc][256][1792]
//   [after part, +1.84 MB)    : Wh f32 [256][1792]
#define WT_BYTES (256u*16384u*2u)

__device__ __forceinline__ unsigned short f2bf(float f){
  union { float f; unsigned u; } x; x.f = f;
  unsigned r = x.u + 0x7fffu + ((x.u >> 16) & 1u);
  return (unsigned short)(r >> 16);
}

// ---------------- Kernel 1: W (16384x256 f32) -> Wt (256x16384 bf16) ----------------
__global__ __launch_bounds__(256) void k_transpose_w(const float* __restrict__ W,
                                                     unsigned short* __restrict__ Wt){
  __shared__ float tile[64][65];
  const int i0 = blockIdx.x * 64;
  const int o0 = blockIdx.y * 64;
  const int tid = threadIdx.x;
  #pragma unroll
  for (int r = 0; r < 16; ++r){
    int il = r*4 + (tid >> 6);
    int ol = tid & 63;
    tile[il][ol] = W[(size_t)(i0+il)*EE + o0 + ol];
  }
  __syncthreads();
  #pragma unroll
  for (int r = 0; r < 16; ++r){
    int ol = r*4 + (tid >> 6);
    int il = tid & 63;
    Wt[(size_t)(o0+ol)*KK + i0 + il] = f2bf(tile[il][ol]);
  }
}

// ---------------- Kernel 2: pipelined GEMM ----------------
// D[o][m] = sum_k Wt[o][k] * hf[m][k].  BK=128 (2 c-planes)/iter, h prefetched
// one iter ahead into VGPRs, LDS double-buffered, ONE barrier per iter.
// grid (32 mt, nkc), 512 thr (8 waves); wave w owns o-rows [w*32, w*32+32).
__global__ __launch_bounds__(512, 4) void k_gemm(const float* __restrict__ h,
                                                 const unsigned short* __restrict__ Wt,
                                                 float* __restrict__ part,
                                                 int cpp /* c-planes per kc chunk */){
  __shared__ unsigned short Bs[2][64*136];   // m x k tile, stride 136 (16B-aligned rows)
  const int tid  = threadIdx.x;
  const int mt   = blockIdx.x;
  const int kc   = blockIdx.y;
  const int n0   = mt * 8;
  const int w    = tid >> 6;
  const int lane = tid & 63;
  const int col  = lane & 15;
  const int quad = lane >> 4;

  // zero pad rows (m = 56..63) in both buffers once
  for (int idx = tid; idx < 1088; idx += 512){
    Bs[0][7616 + idx] = 0;
    Bs[1][7616 + idx] = 0;
  }

  // h staging map: 2 planes x 8 n-rows x 112 float4 = 1792 float4 / 512 thr
  int ghb[4]; short hlds[4][4];
  const bool hv3 = (tid < 256);              // it=3 valid only for tid<256
  #pragma unroll
  for (int it = 0; it < 4; ++it){
    int j  = tid + it*512;
    if (j >= 1792) j = 0;
    int p  = j / 896;
    int jj = j - p*896;
    int nn = jj / 112;
    int f  = jj - nn*112;
    ghb[it] = (n0+nn)*114688 + p*448 + f*4;   // + cbase*448 later
    #pragma unroll
    for (int e = 0; e < 4; ++e){
      int rr = f*4 + e;
      int t_ = rr / 7;
      int v_ = rr - t_*7;
      hlds[it][e] = (short)((nn*7 + v_)*136 + p*64 + t_);
    }
  }

  // A-frag base: row (w*32 + oi*16 + col), 16B at k-offset quad*8
  const unsigned short* aptr = Wt + (size_t)(w*32 + col)*KK + quad*8;

  f32x4 acc[2][4];
  #pragma unroll
  for (int a_ = 0; a_ < 2; ++a_)
    #pragma unroll
    for (int b_ = 0; b_ < 4; ++b_)
      acc[a_][b_] = (f32x4){0.f, 0.f, 0.f, 0.f};

  const int c0    = kc * cpp;      // first c-plane of this chunk
  const int iters = cpp >> 1;      // 2 planes per iteration

  // prologue: h loads for s=0
  float4 hreg[4];
  {
    const int cb = c0*448;
    #pragma unroll
    for (int it = 0; it < 4; ++it)
      if (it < 3 || hv3)
        hreg[it] = *reinterpret_cast<const float4*>(h + (size_t)(ghb[it] + cb));
  }

  int buf = 0;
  for (int s = 0; s < iters; ++s){
    // 1. drain h prefetch into LDS buffer `buf`
    #pragma unroll
    for (int it = 0; it < 4; ++it){
      if (it < 3 || hv3){
        Bs[buf][hlds[it][0]] = f2bf(hreg[it].x);
        Bs[buf][hlds[it][1]] = f2bf(hreg[it].y);
        Bs[buf][hlds[it][2]] = f2bf(hreg[it].z);
        Bs[buf][hlds[it][3]] = f2bf(hreg[it].w);
      }
    }
    // 2. issue A-frag loads for THIS iteration (L2-resident, consumed after barrier)
    const int kb = (c0 + 2*s)*64;
    bf16x8 af[2][4];
    #pragma unroll
    for (int oi = 0; oi < 2; ++oi)
      #pragma unroll
      for (int kh = 0; kh < 4; ++kh)
        af[oi][kh] = *reinterpret_cast<const bf16x8*>(aptr + (size_t)oi*16*KK + kb + kh*32);
    // 3. issue h prefetch for NEXT iteration (HBM latency hidden by step 5)
    if (s + 1 < iters){
      const int cb = (c0 + 2*(s+1))*448;
      #pragma unroll
      for (int it = 0; it < 4; ++it)
        if (it < 3 || hv3)
          hreg[it] = *reinterpret_cast<const float4*>(h + (size_t)(ghb[it] + cb));
    }
    // 4. barrier: Bs[buf] now visible to all waves
    __syncthreads();
    // 5. MFMA over BK=128
    #pragma unroll
    for (int kh = 0; kh < 4; ++kh){
      bf16x8 bfr[4];
      #pragma unroll
      for (int mi = 0; mi < 4; ++mi)
        bfr[mi] = *reinterpret_cast<const bf16x8*>(&Bs[buf][(mi*16 + col)*136 + kh*32 + quad*8]);
      #pragma unroll
      for (int oi = 0; oi < 2; ++oi)
        #pragma unroll
        for (int mi = 0; mi < 4; ++mi)
          acc[oi][mi] = __builtin_amdgcn_mfma_f32_16x16x32_bf16(af[oi][kh], bfr[mi], acc[oi][mi], 0, 0, 0);
    }
    buf ^= 1;
  }

  // partials: part[kc][o][mt*56 + ml], ml < 56 (coalesced, masked tail)
  #pragma unroll
  for (int oi = 0; oi < 2; ++oi){
    #pragma unroll
    for (int r = 0; r < 4; ++r){
      int o = w*32 + oi*16 + quad*4 + r;
      size_t rowbase = ((size_t)(kc*256 + o))*M_USED + mt*56;
      #pragma unroll
      for (int mi = 0; mi < 4; ++mi){
        int ml = mi*16 + col;
        if (ml < 56) part[rowbase + ml] = acc[oi][mi][r];
      }
    }
  }
}

// ---------------- Kernel 3: reduce partials over kc (coalesced in m) ----------------
__global__ __launch_bounds__(256) void k_reduce(const float* __restrict__ part,
                                                float* __restrict__ Wh, int nkc){
  const int m = blockIdx.x*256 + threadIdx.x;
  const int o = blockIdx.y;
  float s = 0.f;
  for (int k = 0; k < nkc; ++k)
    s += part[((size_t)(k*256 + o))*M_USED + m];
  Wh[(size_t)o*M_USED + m] = s;
}

// ---------------- Kernel 4: attention + elu (adj-norm folded in) ----------------
__global__ __launch_bounds__(256) void k_attn(const float* __restrict__ Wh,
                                              const float* __restrict__ a,
                                              const float* __restrict__ Bp,
                                              float* __restrict__ out){
  const int n    = blockIdx.x;
  const int tid  = threadIdx.x;
  const int lane = tid & 63;
  const int wv   = tid >> 6;

  __shared__ float adjn[49];
  __shared__ float red1[4][7], red2[4][7];
  __shared__ float s1s[7], s2s[7];
  __shared__ float att0[49], att[49];

  if (tid == 0){
    float adj[49];
    float mn = 1e30f, mx = -1e30f;
    for (int i = 0; i < 7; ++i)
      for (int j = 0; j < 7; ++j){
        float x = Bp[i*7+j] + 1e-6f + (i == j ? 1.f : 0.f);
        adj[i*7+j] = x;
        mn = fminf(mn, x); mx = fmaxf(mx, x);
      }
    float inv = 1.f / (mx - mn);
    for (int i = 0; i < 49; ++i) adj[i] = (adj[i] - mn) * inv;
    float d12[7];
    for (int i = 0; i < 7; ++i){
      float s = 0.f;
      for (int j = 0; j < 7; ++j) s += adj[i*7+j];
      d12[i] = 1.f / sqrtf(s);
    }
    for (int i = 0; i < 7; ++i)
      for (int j = 0; j < 7; ++j)
        adjn[i*7+j] = d12[i] * adj[i*7+j] * d12[j];
  }

  float wh[7];
  #pragma unroll
  for (int v = 0; v < 7; ++v)
    wh[v] = Wh[(size_t)tid*M_USED + n*7 + v];

  const float a1 = a[tid];
  const float a2 = a[256 + tid];

  #pragma unroll
  for (int v = 0; v < 7; ++v){
    float x1 = wh[v]*a1;
    float x2 = wh[v]*a2;
    #pragma unroll
    for (int off = 32; off > 0; off >>= 1){
      x1 += __shfl_down(x1, off);
      x2 += __shfl_down(x2, off);
    }
    if (lane == 0){ red1[wv][v] = x1; red2[wv][v] = x2; }
  }
  __syncthreads();
  if (tid < 7){
    s1s[tid] = red1[0][tid]+red1[1][tid]+red1[2][tid]+red1[3][tid];
    s2s[tid] = red2[0][tid]+red2[1][tid]+red2[2][tid]+red2[3][tid];
  }
  __syncthreads();
  if (tid < 7){
    const int v = tid;
    float e[7]; float mx = -1e30f;
    #pragma unroll
    for (int u = 0; u < 7; ++u){
      float t = s1s[v] + s2s[u];
      t = t > 0.f ? t : LRELU_ALPHA*t;
      e[u] = t; mx = fmaxf(mx, t);
    }
    float sum = 0.f;
    #pragma unroll
    for (int u = 0; u < 7; ++u){ e[u] = expf(e[u]-mx); sum += e[u]; }
    float inv = 1.f/sum;
    #pragma unroll
    for (int u = 0; u < 7; ++u) att0[v*7+u] = e[u]*inv;
  }
  __syncthreads();
  if (tid < 7){
    const int v = tid;
    #pragma unroll
    for (int u = 0; u < 7; ++u){
      float s = 0.f;
      #pragma unroll
      for (int w7 = 0; w7 < 7; ++w7) s += adjn[v*7+w7]*att0[w7*7+u];
      att[v*7+u] = s;
    }
  }
  __syncthreads();
  #pragma unroll
  for (int v = 0; v < 7; ++v){
    float hp = 0.f;
    #pragma unroll
    for (int u = 0; u < 7; ++u) hp += att[v*7+u]*wh[u];
    float o = hp > 0.f ? hp : expm1f(hp);
    out[(size_t)(n*7+v)*256 + tid] = o;
  }
}

extern "C" void kernel_launch(void* const* d_in, const int* in_sizes, int n_in,
                              void* d_out, int out_size, void* d_ws, size_t ws_size,
                              hipStream_t stream){
  const float* h  = (const float*)d_in[0];
  const float* W  = (const float*)d_in[1];
  const float* a  = (const float*)d_in[2];
  const float* Bp = (const float*)d_in[3];
  float* out = (float*)d_out;
  char* ws = (char*)d_ws;

  const size_t part_elems = (size_t)256 * M_USED;              // per kchunk
  const size_t need16 = WT_BYTES + (16 + 1) * part_elems * 4;  // ~39.6 MB
  const int nkc = (ws_size >= need16) ? 16 : 8;

  unsigned short* Wt   = (unsigned short*)ws;
  float*          part = (float*)(ws + WT_BYTES);
  float*          Wh   = part + (size_t)nkc * part_elems;

  k_transpose_w<<<dim3(256, 4), 256, 0, stream>>>(W, Wt);
  k_gemm<<<dim3(32, nkc), 512, 0, stream>>>(h, Wt, part, 256/nkc);
  k_reduce<<<dim3(7, 256), 256, 0, stream>>>(part, Wh, nkc);
  k_attn<<<256, 256, 0, stream>>>(Wh, a, Bp, out);
}